// Round 7
// baseline (275.399 us; speedup 1.0000x reference)
//
#include <hip/hip_runtime.h>

#define TPB 256
#define BK_SH 8           // 256 nodes per bucket
#define NBMAX 512         // max buckets (n <= 131072)
#define TILE 4096         // edges per bin_scatter tile
#define CAP 8192          // LDS staging capacity per bucket (records)
#define CAPR 16384        // fixed record-region capacity per bucket (4x Poisson mean)

typedef unsigned short ushort_t;
typedef unsigned int uint_t;
typedef __attribute__((ext_vector_type(8))) __bf16 bf8v;
typedef __attribute__((ext_vector_type(4))) float f4v;

__device__ inline ushort_t f2bf(float f) {  // round-to-nearest-even bf16
    uint_t u = __float_as_uint(f);
    return (ushort_t)((u + 0x7FFFu + ((u >> 16) & 1u)) >> 16);
}
__device__ inline uint_t pack2(float a, float b) {
    return (uint_t)f2bf(a) | ((uint_t)f2bf(b) << 16);
}

union u4bf8 {
    uint4 u;
    bf8v b;
};

__device__ inline void addrow(float* acc, uint4 v) {
    acc[0] += __uint_as_float(v.x << 16);
    acc[1] += __uint_as_float(v.x & 0xFFFF0000u);
    acc[2] += __uint_as_float(v.y << 16);
    acc[3] += __uint_as_float(v.y & 0xFFFF0000u);
    acc[4] += __uint_as_float(v.z << 16);
    acc[5] += __uint_as_float(v.z & 0xFFFF0000u);
    acc[6] += __uint_as_float(v.w << 16);
    acc[7] += __uint_as_float(v.w & 0xFFFF0000u);
}

// ========== K1: tile-sort edges by bucket in LDS, flush to fixed regions ==========
// record = (src << 8) | (dst & 255). Bucket regions are fixed-capacity
// [b*CAPR, b*CAPR+CAPR); tiles claim space via bcursor atomics.
__global__ __launch_bounds__(TPB) void bin_scatter_kernel(const int* __restrict__ src,
                                                          const int* __restrict__ dst,
                                                          int* __restrict__ bcursor,
                                                          uint_t* __restrict__ recs,
                                                          int E, int NB) {
    __shared__ uint_t rec[TILE];
    __shared__ ushort_t bb[TILE];
    __shared__ int hist[NBMAX];
    __shared__ int start[NBMAX];
    __shared__ int cur[NBMAX];
    __shared__ int gbase[NBMAX];
    __shared__ int ss[TPB];
    const int tid = threadIdx.x;
    const int t0 = blockIdx.x * TILE;
    const int cnt = min(TILE, E - t0);
    for (int i = tid; i < NBMAX; i += TPB) hist[i] = 0;
    __syncthreads();

    int myS[16], myD[16];
#pragma unroll
    for (int j = 0; j < 16; ++j) {
        int e = t0 + j * TPB + tid;
        if (e < E) {
            myS[j] = src[e];
            myD[j] = dst[e];
            atomicAdd(&hist[myD[j] >> BK_SH], 1);
        } else {
            myD[j] = -1;
        }
    }
    __syncthreads();

    int h0 = hist[2 * tid], h1 = hist[2 * tid + 1];
    int sum2 = h0 + h1;
    ss[tid] = sum2;
    __syncthreads();
    for (int off = 1; off < TPB; off <<= 1) {
        int a = (tid >= off) ? ss[tid - off] : 0;
        __syncthreads();
        ss[tid] += a;
        __syncthreads();
    }
    int ex = ss[tid] - sum2;
    start[2 * tid] = ex;
    start[2 * tid + 1] = ex + h0;
    cur[2 * tid] = ex;
    cur[2 * tid + 1] = ex + h0;
    __syncthreads();

#pragma unroll
    for (int j = 0; j < 16; ++j) {
        if (myD[j] >= 0) {
            int b = myD[j] >> BK_SH;
            int p = atomicAdd(&cur[b], 1);
            rec[p] = ((uint_t)myS[j] << BK_SH) | (uint_t)(myD[j] & ((1 << BK_SH) - 1));
            bb[p] = (ushort_t)b;
        }
    }
    __syncthreads();

    for (int b = tid; b < NB; b += TPB) {
        int c = hist[b];
        gbase[b] = c ? atomicAdd(&bcursor[b], c) : 0;
    }
    __syncthreads();

    for (int i = tid; i < cnt; i += TPB) {
        int b = bb[i];
        recs[gbase[b] + (i - start[b])] = rec[i];
    }
}

// ========== K2: per-bucket: per-node counts, rs, perm, degree-sorted nodeperm ==========
// nodeperm[b*256 + rank] lists the bucket's nodes ordered by degree (invalid
// slots = -1). Mean kernels walk nodes in this order so the 8 octs of a wave
// have near-equal degree -> no exec-mask divergence in the gather loop.
__global__ __launch_bounds__(TPB) void bucket_build_kernel(const uint_t* __restrict__ recs,
                                                           const int* __restrict__ bcursor,
                                                           int* __restrict__ rs_beg,
                                                           int* __restrict__ rs_end,
                                                           int* __restrict__ perm,
                                                           int* __restrict__ nodeperm,
                                                           int n) {
    __shared__ int nh[TPB];
    __shared__ int ncur[TPB];
    __shared__ int sscan[TPB];
    __shared__ int dh[TPB];
    __shared__ int dcur[TPB];
    __shared__ uint_t stage[CAP];
    const int b = blockIdx.x;
    const int tid = threadIdx.x;
    const int gb = b * CAPR;
    const int cnt = bcursor[b] - gb;
    nh[tid] = 0;
    dh[tid] = 0;
    __syncthreads();
    for (int i = tid; i < cnt; i += TPB)
        atomicAdd(&nh[recs[gb + i] & 255], 1);
    __syncthreads();
    int v = nh[tid];
    sscan[tid] = v;
    __syncthreads();
    for (int off = 1; off < TPB; off <<= 1) {
        int a = (tid >= off) ? sscan[tid - off] : 0;
        __syncthreads();
        sscan[tid] += a;
        __syncthreads();
    }
    int ex = sscan[tid] - v;
    int g = (b << BK_SH) + tid;
    if (g < n) {
        rs_beg[g] = gb + ex;
        rs_end[g] = gb + ex + v;
    }
    ncur[tid] = ex;
    // degree histogram for counting sort (invalid nodes pinned to bin 255)
    int key = (g < n) ? min(v, 254) : 255;
    atomicAdd(&dh[key], 1);
    __syncthreads();
    // ---- perm build ----
    if (cnt <= CAP) {
        for (int i = tid; i < cnt; i += TPB) {
            uint_t r = recs[gb + i];
            int p = atomicAdd(&ncur[r & 255], 1);
            stage[p] = r >> BK_SH;
        }
        __syncthreads();
        for (int i = tid; i < cnt; i += TPB)
            perm[gb + i] = (int)stage[i];
    } else {
        for (int i = tid; i < cnt; i += TPB) {
            uint_t r = recs[gb + i];
            int p = atomicAdd(&ncur[r & 255], 1);
            perm[gb + p] = (int)(r >> BK_SH);
        }
    }
    // ---- degree counting sort -> nodeperm ----
    int dv = dh[tid];
    sscan[tid] = dv;
    __syncthreads();
    for (int off = 1; off < TPB; off <<= 1) {
        int a = (tid >= off) ? sscan[tid - off] : 0;
        __syncthreads();
        sscan[tid] += a;
        __syncthreads();
    }
    dcur[tid] = sscan[tid] - dv;
    __syncthreads();
    int rank = atomicAdd(&dcur[key], 1);
    nodeperm[(b << BK_SH) + rank] = (g < n) ? g : -1;
}

// ========== weight convert + cursor seed (launched FIRST) ==========
// Wl1b/Wr1b: [64][128] bf16. Wcat: [128][128] bf16, k<64 from Wl2, k>=64 from Wr2.
// Threads 0..NBMAX-1 additionally seed bcursor to fixed region bases.
__global__ __launch_bounds__(TPB) void cvt_w_kernel(const float* __restrict__ Wl1,
                                                    const float* __restrict__ Wr1,
                                                    const float* __restrict__ Wl2,
                                                    const float* __restrict__ Wr2,
                                                    ushort_t* __restrict__ wl1b,
                                                    ushort_t* __restrict__ wr1b,
                                                    ushort_t* __restrict__ wcat,
                                                    int* __restrict__ bcursor) {
    int i = blockIdx.x * TPB + threadIdx.x;  // 0..16383
    if (i < NBMAX) bcursor[i] = i * CAPR;
    if (i < 8192) {
        wl1b[i] = f2bf(Wl1[i]);
        wr1b[i] = f2bf(Wr1[i]);
    }
    if (i < 16384) {
        int c = i >> 7, k = i & 127;
        wcat[i] = (k < 64) ? f2bf(Wl2[c * 64 + k]) : f2bf(Wr2[c * 64 + (k - 64)]);
    }
}

// ========== Dual MFMA GEMM: one pass over x computes BOTH layer-1 products ==========
// y1b[g][c] = bf16(sum_k x[g][k]*Wl[c][k]);  zf[g][c] = f32(sum_k x[g][k]*Wr[c][k]).
// A is f32 in memory, converted to bf16 in-register. K=128, N=64.
// Block = 4 waves x 32 nodes = 128 nodes.
__global__ __launch_bounds__(TPB) void dual_lin_kernel(
    const float* __restrict__ xf, const ushort_t* __restrict__ Wl,
    const ushort_t* __restrict__ Wr, ushort_t* __restrict__ y1b,
    float* __restrict__ zf, int n) {
    const int wave = threadIdx.x >> 6;
    const int lane = threadIdx.x & 63;
    const int l16 = lane & 15;
    const int quad = lane >> 4;
    const int node0 = blockIdx.x * 128 + wave * 32;
    const int koff = quad * 8;

    bf8v wl[4][4], wr[4][4];
#pragma unroll
    for (int ct = 0; ct < 4; ++ct)
#pragma unroll
        for (int kt = 0; kt < 4; ++kt) {
            wl[ct][kt] = *(const bf8v*)(Wl + (ct * 16 + l16) * 128 + kt * 32 + koff);
            wr[ct][kt] = *(const bf8v*)(Wr + (ct * 16 + l16) * 128 + kt * 32 + koff);
        }

    f4v accY[2][4], accZ[2][4];
#pragma unroll
    for (int mt = 0; mt < 2; ++mt)
#pragma unroll
        for (int ct = 0; ct < 4; ++ct) {
            accY[mt][ct] = (f4v)(0.0f);
            accZ[mt][ct] = (f4v)(0.0f);
        }

#pragma unroll
    for (int mt = 0; mt < 2; ++mt) {
        int row = node0 + mt * 16 + l16;
        row = min(row, n - 1);
        bf8v a[4];
#pragma unroll
        for (int kt = 0; kt < 4; ++kt) {
            const float* p = xf + (long long)row * 128 + kt * 32 + koff;
            float4 f0 = *(const float4*)(p);
            float4 f1 = *(const float4*)(p + 4);
            u4bf8 cvt;
            cvt.u.x = pack2(f0.x, f0.y);
            cvt.u.y = pack2(f0.z, f0.w);
            cvt.u.z = pack2(f1.x, f1.y);
            cvt.u.w = pack2(f1.z, f1.w);
            a[kt] = cvt.b;
        }
#pragma unroll
        for (int ct = 0; ct < 4; ++ct)
#pragma unroll
            for (int kt = 0; kt < 4; ++kt) {
                accY[mt][ct] = __builtin_amdgcn_mfma_f32_16x16x32_bf16(
                    a[kt], wl[ct][kt], accY[mt][ct], 0, 0, 0);
                accZ[mt][ct] = __builtin_amdgcn_mfma_f32_16x16x32_bf16(
                    a[kt], wr[ct][kt], accZ[mt][ct], 0, 0, 0);
            }
    }

    // D layout: col = lane&15, row = quad*4 + r
#pragma unroll
    for (int ct = 0; ct < 4; ++ct) {
        const int col = ct * 16 + l16;
#pragma unroll
        for (int mt = 0; mt < 2; ++mt) {
            int rbase = node0 + mt * 16 + quad * 4;
#pragma unroll
            for (int r = 0; r < 4; ++r) {
                int g = rbase + r;
                if (g >= n) continue;
                y1b[(long long)g * 64 + col] = f2bf(accY[mt][ct][r]);
                zf[(long long)g * 64 + col] = accZ[mt][ct][r];
            }
        }
    }
}

// ========== MFMA out: out[g][C] = [m2b|hb] @ Wcat^T + b2, K=128, N=128 ==========
// Block = 4 waves; each wave owns 32 cols, all waves cover the same 64 nodes.
__global__ __launch_bounds__(TPB) void out_mfma_kernel(
    const ushort_t* __restrict__ m2b, const ushort_t* __restrict__ hb,
    const ushort_t* __restrict__ Wc, const float* __restrict__ b2,
    float* __restrict__ out, int n) {
    const int wave = threadIdx.x >> 6;
    const int lane = threadIdx.x & 63;
    const int l16 = lane & 15;
    const int quad = lane >> 4;
    const int cb = wave * 32;
    const int node0 = blockIdx.x * 64;
    const int koff = quad * 8;

    bf8v wb[2][4];
#pragma unroll
    for (int ct = 0; ct < 2; ++ct)
#pragma unroll
        for (int kt = 0; kt < 4; ++kt)
            wb[ct][kt] = *(const bf8v*)(Wc + (cb + ct * 16 + l16) * 128 + kt * 32 + koff);

    f4v acc[4][2];
#pragma unroll
    for (int mt = 0; mt < 4; ++mt)
#pragma unroll
        for (int ct = 0; ct < 2; ++ct) acc[mt][ct] = (f4v)(0.0f);

#pragma unroll
    for (int mt = 0; mt < 4; ++mt) {
        int row = node0 + mt * 16 + l16;
        row = min(row, n - 1);
        bf8v a[4];
        a[0] = *(const bf8v*)(m2b + (long long)row * 64 + koff);
        a[1] = *(const bf8v*)(m2b + (long long)row * 64 + 32 + koff);
        a[2] = *(const bf8v*)(hb + (long long)row * 64 + koff);
        a[3] = *(const bf8v*)(hb + (long long)row * 64 + 32 + koff);
#pragma unroll
        for (int ct = 0; ct < 2; ++ct)
#pragma unroll
            for (int kt = 0; kt < 4; ++kt)
                acc[mt][ct] = __builtin_amdgcn_mfma_f32_16x16x32_bf16(
                    a[kt], wb[ct][kt], acc[mt][ct], 0, 0, 0);
    }

#pragma unroll
    for (int ct = 0; ct < 2; ++ct) {
        const int col = cb + ct * 16 + l16;
        const float bv = b2[col];
#pragma unroll
        for (int mt = 0; mt < 4; ++mt) {
            int rbase = node0 + mt * 16 + quad * 4;
#pragma unroll
            for (int r = 0; r < 4; ++r) {
                int g = rbase + r;
                if (g >= n) continue;
                __builtin_nontemporal_store(acc[mt][ct][r] + bv,
                                            &out[(long long)g * 128 + col]);
            }
        }
    }
}

// ====== mean aggregation over bf16 feature rows, via CSR: one OCT per node ======
// Octs are assigned nodes in DEGREE-SORTED order via nodeperm: the 8 octs of a
// wave have near-equal degree, so the gather loop runs without exec-mask waste.
// 8 lanes (cl) cover the 128B row; 8-deep unrolled gathers.
// FUSE=1: outb = bf16(relu(mean + zf + bias))  [layer-1 epilogue, hb]
// FUSE=0: outb = bf16(mean)                    [m2b]
template <int FUSE>
__global__ __launch_bounds__(TPB) void csr_mean8_kernel(
    const ushort_t* __restrict__ feat, const int* __restrict__ rs_beg,
    const int* __restrict__ rs_end, const int* __restrict__ perm,
    const int* __restrict__ nodeperm, const float* __restrict__ zf,
    const float* __restrict__ bias, ushort_t* __restrict__ outb, int nperm) {
    long long gt = (long long)blockIdx.x * TPB + threadIdx.x;
    int idx = (int)(gt >> 3);
    if (idx >= nperm) return;
    int w = nodeperm[idx];
    if (w < 0) return;
    const int cl = threadIdx.x & 7;
    const int beg = rs_beg[w], end = rs_end[w];
    float acc[8];
#pragma unroll
    for (int j = 0; j < 8; ++j) acc[j] = 0.0f;
    const uint4* fp = (const uint4*)feat;
    int e = beg;
    for (; e + 8 <= end; e += 8) {
        int s[8];
#pragma unroll
        for (int j = 0; j < 8; ++j) s[j] = perm[e + j];
        uint4 v[8];
#pragma unroll
        for (int j = 0; j < 8; ++j) v[j] = fp[((long long)s[j] << 3) + cl];
#pragma unroll
        for (int j = 0; j < 8; ++j) addrow(acc, v[j]);
    }
    for (; e + 4 <= end; e += 4) {
        int s0 = perm[e];
        int s1 = perm[e + 1];
        int s2 = perm[e + 2];
        int s3 = perm[e + 3];
        uint4 v0 = fp[((long long)s0 << 3) + cl];
        uint4 v1 = fp[((long long)s1 << 3) + cl];
        uint4 v2 = fp[((long long)s2 << 3) + cl];
        uint4 v3 = fp[((long long)s3 << 3) + cl];
        addrow(acc, v0);
        addrow(acc, v1);
        addrow(acc, v2);
        addrow(acc, v3);
    }
    for (; e < end; ++e) {
        int s = perm[e];
        uint4 v = fp[((long long)s << 3) + cl];
        addrow(acc, v);
    }
    float d = (float)(end - beg);
    float inv = d > 0.f ? 1.f / d : 0.f;
    float r[8];
#pragma unroll
    for (int j = 0; j < 8; ++j) r[j] = acc[j] * inv;
    if (FUSE) {
        const float* zp = zf + (long long)w * 64 + cl * 8;
        float4 z0 = *(const float4*)(zp);
        float4 z1 = *(const float4*)(zp + 4);
        const float* bp = bias + cl * 8;
        float4 b0 = *(const float4*)(bp);
        float4 b1v = *(const float4*)(bp + 4);
        r[0] = fmaxf(r[0] + z0.x + b0.x, 0.0f);
        r[1] = fmaxf(r[1] + z0.y + b0.y, 0.0f);
        r[2] = fmaxf(r[2] + z0.z + b0.z, 0.0f);
        r[3] = fmaxf(r[3] + z0.w + b0.w, 0.0f);
        r[4] = fmaxf(r[4] + z1.x + b1v.x, 0.0f);
        r[5] = fmaxf(r[5] + z1.y + b1v.y, 0.0f);
        r[6] = fmaxf(r[6] + z1.z + b1v.z, 0.0f);
        r[7] = fmaxf(r[7] + z1.w + b1v.w, 0.0f);
    }
    uint4 o4;
    o4.x = pack2(r[0], r[1]);
    o4.y = pack2(r[2], r[3]);
    o4.z = pack2(r[4], r[5]);
    o4.w = pack2(r[6], r[7]);
    ((uint4*)(outb + (long long)w * 64))[cl] = o4;
}

extern "C" void kernel_launch(void* const* d_in, const int* in_sizes, int n_in,
                              void* d_out, int out_size, void* d_ws, size_t ws_size,
                              hipStream_t stream) {
    const float* x = (const float*)d_in[0];
    const int* ei = (const int*)d_in[1];
    const float* Wl1 = (const float*)d_in[2];
    const float* Wr1 = (const float*)d_in[3];
    const float* b1 = (const float*)d_in[4];
    const float* Wl2 = (const float*)d_in[5];
    const float* Wr2 = (const float*)d_in[6];
    const float* b2 = (const float*)d_in[7];
    float* out = (float*)d_out;

    const int n = in_sizes[0] / 128;   // 100000
    const int E = in_sizes[1] / 2;     // 1600000
    const int* src = ei;
    const int* dst = ei + E;
    const int NB = (n + 255) >> BK_SH;
    const int nperm = NB << BK_SH;

    // workspace (4B units, 64-aligned):
    // bcursor[512] | rs_beg[n] | rs_end[n] | nodeperm[NB*256] | recs[NB*CAPR]
    //   | perm[NB*CAPR] | wl1b | wr1b | wcat | fb[n*64 bf16 = y1b]
    //   | hbuf[n*64 bf16 = hb] | zf[n*64 f32; m2b aliases zf]
    char* wsb = (char*)d_ws;
    auto A = [](size_t v) { return (v + 63) & ~(size_t)63; };
    int* bcursor = (int*)wsb;                      size_t o = NBMAX;
    int* rs_beg = (int*)wsb + o;                   o += A(n);
    int* rs_end = (int*)wsb + o;                   o += A(n);
    int* nodeperm = (int*)wsb + o;                 o += A(nperm);
    uint_t* recs = (uint_t*)((int*)wsb + o);       o += (size_t)NB * CAPR;
    int* perm = (int*)wsb + o;                     o += (size_t)NB * CAPR;
    ushort_t* wl1b = (ushort_t*)((int*)wsb + o);   o += 4096;
    ushort_t* wr1b = (ushort_t*)((int*)wsb + o);   o += 4096;
    ushort_t* wcat = (ushort_t*)((int*)wsb + o);   o += 8192;
    ushort_t* fb = (ushort_t*)((int*)wsb + o);     o += A((size_t)n * 32);
    ushort_t* hbuf = (ushort_t*)((int*)wsb + o);   o += A((size_t)n * 32);
    float* zf = (float*)wsb + o;                   // n*64 f32
    ushort_t* m2b = (ushort_t*)zf;                 // aliases zf (dead after mean1)

    // ---- weight conversion + cursor seed (first: seeds bcursor for scatter) ----
    cvt_w_kernel<<<64, TPB, 0, stream>>>(Wl1, Wr1, Wl2, Wr2, wl1b, wr1b, wcat, bcursor);

    // ---- CSR build: fixed-capacity bucket regions + degree-sorted nodeperm ----
    bin_scatter_kernel<<<(E + TILE - 1) / TILE, TPB, 0, stream>>>(src, dst, bcursor, recs, E, NB);
    bucket_build_kernel<<<NB, TPB, 0, stream>>>(recs, bcursor, rs_beg, rs_end, perm, nodeperm, n);

    const int lblocks = (n + 127) / 128;
    const int mblocks = (int)(((long long)nperm * 8 + TPB - 1) / TPB);
    const int oblocks = (n + 63) / 64;

    // y1b = bf16(x @ Wl1^T), zf = f32(x @ Wr1^T)  -- x read once
    dual_lin_kernel<<<lblocks, TPB, 0, stream>>>(x, wl1b, wr1b, fb, zf, n);
    // hb = bf16(relu(mean(y1b) + b1 + zf))  (fused layer-1 epilogue)
    csr_mean8_kernel<1><<<mblocks, TPB, 0, stream>>>(fb, rs_beg, rs_end, perm, nodeperm, zf, b1, hbuf, nperm);
    // m2b = bf16(mean(hb))  (zf dead -> aliased)
    csr_mean8_kernel<0><<<mblocks, TPB, 0, stream>>>(hbuf, rs_beg, rs_end, perm, nodeperm, nullptr, nullptr, m2b, nperm);
    // out = [m2b|hb] @ wcat^T + b2
    out_mfma_kernel<<<oblocks, TPB, 0, stream>>>(m2b, hbuf, wcat, b2, out, n);
}

// Round 8
// 240.559 us; speedup vs baseline: 1.1448x; 1.1448x over previous
//
#include <hip/hip_runtime.h>

#define TPB 256
#define BK_SH 8           // 256 nodes per bucket
#define NBMAX 512         // max buckets (n <= 131072)
#define TILE 4096         // edges per bin_scatter tile
#define CAP 8192          // LDS staging capacity per bucket (records)
#define CAPR 16384        // fixed record-region capacity per bucket (4x Poisson mean)
#define M2LD 72           // LDS row stride (ushorts) for fused m2 tile (16B-aligned, bank-uniform)

typedef unsigned short ushort_t;
typedef unsigned int uint_t;
typedef __attribute__((ext_vector_type(8))) __bf16 bf8v;
typedef __attribute__((ext_vector_type(4))) float f4v;

__device__ inline ushort_t f2bf(float f) {  // round-to-nearest-even bf16
    uint_t u = __float_as_uint(f);
    return (ushort_t)((u + 0x7FFFu + ((u >> 16) & 1u)) >> 16);
}
__device__ inline uint_t pack2(float a, float b) {
    return (uint_t)f2bf(a) | ((uint_t)f2bf(b) << 16);
}

union u4bf8 {
    uint4 u;
    bf8v b;
};

__device__ inline void addrow(float* acc, uint4 v) {
    acc[0] += __uint_as_float(v.x << 16);
    acc[1] += __uint_as_float(v.x & 0xFFFF0000u);
    acc[2] += __uint_as_float(v.y << 16);
    acc[3] += __uint_as_float(v.y & 0xFFFF0000u);
    acc[4] += __uint_as_float(v.z << 16);
    acc[5] += __uint_as_float(v.z & 0xFFFF0000u);
    acc[6] += __uint_as_float(v.w << 16);
    acc[7] += __uint_as_float(v.w & 0xFFFF0000u);
}

// ========== weight convert + cursor seed (launched FIRST) ==========
__global__ __launch_bounds__(TPB) void cvt_w_kernel(const float* __restrict__ Wl1,
                                                    const float* __restrict__ Wr1,
                                                    const float* __restrict__ Wl2,
                                                    const float* __restrict__ Wr2,
                                                    ushort_t* __restrict__ wl1b,
                                                    ushort_t* __restrict__ wr1b,
                                                    ushort_t* __restrict__ wcat,
                                                    int* __restrict__ bcursor) {
    int i = blockIdx.x * TPB + threadIdx.x;  // 0..16383
    if (i < NBMAX) bcursor[i] = i * CAPR;
    if (i < 8192) {
        wl1b[i] = f2bf(Wl1[i]);
        wr1b[i] = f2bf(Wr1[i]);
    }
    if (i < 16384) {
        int c = i >> 7, k = i & 127;
        wcat[i] = (k < 64) ? f2bf(Wl2[c * 64 + k]) : f2bf(Wr2[c * 64 + (k - 64)]);
    }
}

// ========== FAT kernel: blocks < SB run bin_scatter; the rest run dual_lin ==========
// Both halves depend only on cvt_w (bcursor seed / converted weights) and are
// mutually independent -> they co-schedule across CUs instead of serializing.
struct ScatterSmem {
    uint_t rec[TILE];
    ushort_t bb[TILE];
    int hist[NBMAX];
    int start[NBMAX];
    int cur[NBMAX];
    int gbase[NBMAX];
    int ss[TPB];
};

__global__ __launch_bounds__(TPB) void fat_kernel(
    const int* __restrict__ src, const int* __restrict__ dst,
    int* __restrict__ bcursor, uint_t* __restrict__ recs, int E, int NB, int SB,
    const float* __restrict__ xf, const ushort_t* __restrict__ Wl,
    const ushort_t* __restrict__ Wr, ushort_t* __restrict__ y1b,
    float* __restrict__ zf, int n) {
    __shared__ ScatterSmem sm;
    const int tid = threadIdx.x;
    if ((int)blockIdx.x < SB) {
        // ---------- bin_scatter: record = (src << 8) | (dst & 255) ----------
        const int t0 = blockIdx.x * TILE;
        const int cnt = min(TILE, E - t0);
        for (int i = tid; i < NBMAX; i += TPB) sm.hist[i] = 0;
        __syncthreads();

        int myS[16], myD[16];
#pragma unroll
        for (int j = 0; j < 16; ++j) {
            int e = t0 + j * TPB + tid;
            if (e < E) {
                myS[j] = src[e];
                myD[j] = dst[e];
                atomicAdd(&sm.hist[myD[j] >> BK_SH], 1);
            } else {
                myD[j] = -1;
            }
        }
        __syncthreads();

        int h0 = sm.hist[2 * tid], h1 = sm.hist[2 * tid + 1];
        int sum2 = h0 + h1;
        sm.ss[tid] = sum2;
        __syncthreads();
        for (int off = 1; off < TPB; off <<= 1) {
            int a = (tid >= off) ? sm.ss[tid - off] : 0;
            __syncthreads();
            sm.ss[tid] += a;
            __syncthreads();
        }
        int ex = sm.ss[tid] - sum2;
        sm.start[2 * tid] = ex;
        sm.start[2 * tid + 1] = ex + h0;
        sm.cur[2 * tid] = ex;
        sm.cur[2 * tid + 1] = ex + h0;
        __syncthreads();

#pragma unroll
        for (int j = 0; j < 16; ++j) {
            if (myD[j] >= 0) {
                int b = myD[j] >> BK_SH;
                int p = atomicAdd(&sm.cur[b], 1);
                sm.rec[p] = ((uint_t)myS[j] << BK_SH) | (uint_t)(myD[j] & ((1 << BK_SH) - 1));
                sm.bb[p] = (ushort_t)b;
            }
        }
        __syncthreads();

        for (int b = tid; b < NB; b += TPB) {
            int c = sm.hist[b];
            sm.gbase[b] = c ? atomicAdd(&bcursor[b], c) : 0;
        }
        __syncthreads();

        for (int i = tid; i < cnt; i += TPB) {
            int b = sm.bb[i];
            recs[sm.gbase[b] + (i - sm.start[b])] = sm.rec[i];
        }
    } else {
        // ---------- dual_lin: y1b = bf16(x@Wl^T), zf = f32(x@Wr^T) ----------
        const int wave = tid >> 6;
        const int lane = tid & 63;
        const int l16 = lane & 15;
        const int quad = lane >> 4;
        const int node0 = ((int)blockIdx.x - SB) * 128 + wave * 32;
        const int koff = quad * 8;

        bf8v wl[4][4], wr[4][4];
#pragma unroll
        for (int ct = 0; ct < 4; ++ct)
#pragma unroll
            for (int kt = 0; kt < 4; ++kt) {
                wl[ct][kt] = *(const bf8v*)(Wl + (ct * 16 + l16) * 128 + kt * 32 + koff);
                wr[ct][kt] = *(const bf8v*)(Wr + (ct * 16 + l16) * 128 + kt * 32 + koff);
            }

        f4v accY[2][4], accZ[2][4];
#pragma unroll
        for (int mt = 0; mt < 2; ++mt)
#pragma unroll
            for (int ct = 0; ct < 4; ++ct) {
                accY[mt][ct] = (f4v)(0.0f);
                accZ[mt][ct] = (f4v)(0.0f);
            }

#pragma unroll
        for (int mt = 0; mt < 2; ++mt) {
            int row = node0 + mt * 16 + l16;
            row = min(row, n - 1);
            bf8v a[4];
#pragma unroll
            for (int kt = 0; kt < 4; ++kt) {
                const float* p = xf + (long long)row * 128 + kt * 32 + koff;
                float4 f0 = *(const float4*)(p);
                float4 f1 = *(const float4*)(p + 4);
                u4bf8 cvt;
                cvt.u.x = pack2(f0.x, f0.y);
                cvt.u.y = pack2(f0.z, f0.w);
                cvt.u.z = pack2(f1.x, f1.y);
                cvt.u.w = pack2(f1.z, f1.w);
                a[kt] = cvt.b;
            }
#pragma unroll
            for (int ct = 0; ct < 4; ++ct)
#pragma unroll
                for (int kt = 0; kt < 4; ++kt) {
                    accY[mt][ct] = __builtin_amdgcn_mfma_f32_16x16x32_bf16(
                        a[kt], wl[ct][kt], accY[mt][ct], 0, 0, 0);
                    accZ[mt][ct] = __builtin_amdgcn_mfma_f32_16x16x32_bf16(
                        a[kt], wr[ct][kt], accZ[mt][ct], 0, 0, 0);
                }
        }

#pragma unroll
        for (int ct = 0; ct < 4; ++ct) {
            const int col = ct * 16 + l16;
#pragma unroll
            for (int mt = 0; mt < 2; ++mt) {
                int rbase = node0 + mt * 16 + quad * 4;
#pragma unroll
                for (int r = 0; r < 4; ++r) {
                    int g = rbase + r;
                    if (g >= n) continue;
                    y1b[(long long)g * 64 + col] = f2bf(accY[mt][ct][r]);
                    zf[(long long)g * 64 + col] = accZ[mt][ct][r];
                }
            }
        }
    }
}

// ========== per-bucket: per-node counts, rs_beg/rs_end, perm ==========
__global__ __launch_bounds__(TPB) void bucket_build_kernel(const uint_t* __restrict__ recs,
                                                           const int* __restrict__ bcursor,
                                                           int* __restrict__ rs_beg,
                                                           int* __restrict__ rs_end,
                                                           int* __restrict__ perm, int n) {
    __shared__ int nh[TPB];
    __shared__ int ncur[TPB];
    __shared__ int sscan[TPB];
    __shared__ uint_t stage[CAP];
    const int b = blockIdx.x;
    const int tid = threadIdx.x;
    const int gb = b * CAPR;
    const int cnt = bcursor[b] - gb;
    nh[tid] = 0;
    __syncthreads();
    for (int i = tid; i < cnt; i += TPB)
        atomicAdd(&nh[recs[gb + i] & 255], 1);
    __syncthreads();
    int v = nh[tid];
    sscan[tid] = v;
    __syncthreads();
    for (int off = 1; off < TPB; off <<= 1) {
        int a = (tid >= off) ? sscan[tid - off] : 0;
        __syncthreads();
        sscan[tid] += a;
        __syncthreads();
    }
    int ex = sscan[tid] - v;
    int g = (b << BK_SH) + tid;
    if (g < n) {
        rs_beg[g] = gb + ex;
        rs_end[g] = gb + ex + v;
    }
    ncur[tid] = ex;
    __syncthreads();
    if (cnt <= CAP) {
        for (int i = tid; i < cnt; i += TPB) {
            uint_t r = recs[gb + i];
            int p = atomicAdd(&ncur[r & 255], 1);
            stage[p] = r >> BK_SH;
        }
        __syncthreads();
        for (int i = tid; i < cnt; i += TPB)
            perm[gb + i] = (int)stage[i];
    } else {
        for (int i = tid; i < cnt; i += TPB) {
            uint_t r = recs[gb + i];
            int p = atomicAdd(&ncur[r & 255], 1);
            perm[gb + p] = (int)(r >> BK_SH);
        }
    }
}

// ====== mean1 (fused layer-1 epilogue): hb = bf16(relu(mean(y1b) + zf + b1)) ======
// One oct per node; 8 lanes cover the 128B row; 8-deep unrolled gathers.
__global__ __launch_bounds__(TPB) void csr_mean8_kernel(
    const ushort_t* __restrict__ feat, const int* __restrict__ rs_beg,
    const int* __restrict__ rs_end, const int* __restrict__ perm,
    const float* __restrict__ zf, const float* __restrict__ bias,
    ushort_t* __restrict__ outb, int n) {
    long long gt = (long long)blockIdx.x * TPB + threadIdx.x;
    int w = (int)(gt >> 3);
    if (w >= n) return;
    const int cl = threadIdx.x & 7;
    const int beg = rs_beg[w], end = rs_end[w];
    float acc[8];
#pragma unroll
    for (int j = 0; j < 8; ++j) acc[j] = 0.0f;
    const uint4* fp = (const uint4*)feat;
    int e = beg;
    for (; e + 8 <= end; e += 8) {
        int s[8];
#pragma unroll
        for (int j = 0; j < 8; ++j) s[j] = perm[e + j];
        uint4 v[8];
#pragma unroll
        for (int j = 0; j < 8; ++j) v[j] = fp[((long long)s[j] << 3) + cl];
#pragma unroll
        for (int j = 0; j < 8; ++j) addrow(acc, v[j]);
    }
    for (; e + 4 <= end; e += 4) {
        int s0 = perm[e], s1 = perm[e + 1], s2 = perm[e + 2], s3 = perm[e + 3];
        uint4 v0 = fp[((long long)s0 << 3) + cl];
        uint4 v1 = fp[((long long)s1 << 3) + cl];
        uint4 v2 = fp[((long long)s2 << 3) + cl];
        uint4 v3 = fp[((long long)s3 << 3) + cl];
        addrow(acc, v0);
        addrow(acc, v1);
        addrow(acc, v2);
        addrow(acc, v3);
    }
    for (; e < end; ++e) {
        int s = perm[e];
        uint4 v = fp[((long long)s << 3) + cl];
        addrow(acc, v);
    }
    float d = (float)(end - beg);
    float inv = d > 0.f ? 1.f / d : 0.f;
    float r[8];
#pragma unroll
    for (int j = 0; j < 8; ++j) r[j] = acc[j] * inv;
    const float* zp = zf + (long long)w * 64 + cl * 8;
    float4 z0 = *(const float4*)(zp);
    float4 z1 = *(const float4*)(zp + 4);
    const float* bp = bias + cl * 8;
    float4 b0 = *(const float4*)(bp);
    float4 b1v = *(const float4*)(bp + 4);
    r[0] = fmaxf(r[0] + z0.x + b0.x, 0.0f);
    r[1] = fmaxf(r[1] + z0.y + b0.y, 0.0f);
    r[2] = fmaxf(r[2] + z0.z + b0.z, 0.0f);
    r[3] = fmaxf(r[3] + z0.w + b0.w, 0.0f);
    r[4] = fmaxf(r[4] + z1.x + b1v.x, 0.0f);
    r[5] = fmaxf(r[5] + z1.y + b1v.y, 0.0f);
    r[6] = fmaxf(r[6] + z1.z + b1v.z, 0.0f);
    r[7] = fmaxf(r[7] + z1.w + b1v.w, 0.0f);
    uint4 o4;
    o4.x = pack2(r[0], r[1]);
    o4.y = pack2(r[2], r[3]);
    o4.z = pack2(r[4], r[5]);
    o4.w = pack2(r[6], r[7]);
    ((uint4*)(outb + (long long)w * 64))[cl] = o4;
}

// ========== FUSED mean2 + out GEMM ==========
// Block owns 64 nodes. Phase 1: 32 octs x 2 halves compute mean(hb) rows ->
// bf16 into LDS tile m2[64][M2LD]. Phase 2: out[g][:] = [m2|hb] @ Wcat^T + b2
// with A-fragments a[0..1] from LDS, a[2..3] from global hb.
__global__ __launch_bounds__(TPB) void out_fused_kernel(
    const ushort_t* __restrict__ hb, const int* __restrict__ rs_beg,
    const int* __restrict__ rs_end, const int* __restrict__ perm,
    const ushort_t* __restrict__ Wc, const float* __restrict__ b2,
    float* __restrict__ out, int n) {
    __shared__ ushort_t m2[64 * M2LD];
    const int tid = threadIdx.x;
    const int node0 = blockIdx.x * 64;
    const int oct = tid >> 3;   // 0..31
    const int cl = tid & 7;
    const uint4* fp = (const uint4*)hb;

    // ---- phase 1: mean rows ----
#pragma unroll
    for (int half = 0; half < 2; ++half) {
        int widx = oct + half * 32;       // 0..63
        int w = node0 + widx;
        float acc[8];
#pragma unroll
        for (int j = 0; j < 8; ++j) acc[j] = 0.0f;
        float inv = 0.0f;
        if (w < n) {
            const int beg = rs_beg[w], end = rs_end[w];
            int e = beg;
            for (; e + 8 <= end; e += 8) {
                int s[8];
#pragma unroll
                for (int j = 0; j < 8; ++j) s[j] = perm[e + j];
                uint4 v[8];
#pragma unroll
                for (int j = 0; j < 8; ++j) v[j] = fp[((long long)s[j] << 3) + cl];
#pragma unroll
                for (int j = 0; j < 8; ++j) addrow(acc, v[j]);
            }
            for (; e + 4 <= end; e += 4) {
                int s0 = perm[e], s1 = perm[e + 1], s2 = perm[e + 2], s3 = perm[e + 3];
                uint4 v0 = fp[((long long)s0 << 3) + cl];
                uint4 v1 = fp[((long long)s1 << 3) + cl];
                uint4 v2 = fp[((long long)s2 << 3) + cl];
                uint4 v3 = fp[((long long)s3 << 3) + cl];
                addrow(acc, v0);
                addrow(acc, v1);
                addrow(acc, v2);
                addrow(acc, v3);
            }
            for (; e < end; ++e) {
                int s = perm[e];
                uint4 v = fp[((long long)s << 3) + cl];
                addrow(acc, v);
            }
            float d = (float)(end - beg);
            inv = d > 0.f ? 1.f / d : 0.f;
        }
        uint4 o4;
        o4.x = pack2(acc[0] * inv, acc[1] * inv);
        o4.y = pack2(acc[2] * inv, acc[3] * inv);
        o4.z = pack2(acc[4] * inv, acc[5] * inv);
        o4.w = pack2(acc[6] * inv, acc[7] * inv);
        *(uint4*)(m2 + widx * M2LD + cl * 8) = o4;
    }
    __syncthreads();

    // ---- phase 2: out MFMA ----
    const int wave = tid >> 6;
    const int lane = tid & 63;
    const int l16 = lane & 15;
    const int quad = lane >> 4;
    const int cb = wave * 32;
    const int koff = quad * 8;

    bf8v wb[2][4];
#pragma unroll
    for (int ct = 0; ct < 2; ++ct)
#pragma unroll
        for (int kt = 0; kt < 4; ++kt)
            wb[ct][kt] = *(const bf8v*)(Wc + (cb + ct * 16 + l16) * 128 + kt * 32 + koff);

    f4v acc2[4][2];
#pragma unroll
    for (int mt = 0; mt < 4; ++mt)
#pragma unroll
        for (int ct = 0; ct < 2; ++ct) acc2[mt][ct] = (f4v)(0.0f);

#pragma unroll
    for (int mt = 0; mt < 4; ++mt) {
        int rl = mt * 16 + l16;           // local row 0..63
        int row = min(node0 + rl, n - 1); // global row for hb
        bf8v a[4];
        a[0] = *(const bf8v*)(m2 + rl * M2LD + koff);
        a[1] = *(const bf8v*)(m2 + rl * M2LD + 32 + koff);
        a[2] = *(const bf8v*)(hb + (long long)row * 64 + koff);
        a[3] = *(const bf8v*)(hb + (long long)row * 64 + 32 + koff);
#pragma unroll
        for (int ct = 0; ct < 2; ++ct)
#pragma unroll
            for (int kt = 0; kt < 4; ++kt)
                acc2[mt][ct] = __builtin_amdgcn_mfma_f32_16x16x32_bf16(
                    a[kt], wb[ct][kt], acc2[mt][ct], 0, 0, 0);
    }

#pragma unroll
    for (int ct = 0; ct < 2; ++ct) {
        const int col = cb + ct * 16 + l16;
        const float bv = b2[col];
#pragma unroll
        for (int mt = 0; mt < 4; ++mt) {
            int rbase = node0 + mt * 16 + quad * 4;
#pragma unroll
            for (int r = 0; r < 4; ++r) {
                int g = rbase + r;
                if (g >= n) continue;
                __builtin_nontemporal_store(acc2[mt][ct][r] + bv,
                                            &out[(long long)g * 128 + col]);
            }
        }
    }
}

extern "C" void kernel_launch(void* const* d_in, const int* in_sizes, int n_in,
                              void* d_out, int out_size, void* d_ws, size_t ws_size,
                              hipStream_t stream) {
    const float* x = (const float*)d_in[0];
    const int* ei = (const int*)d_in[1];
    const float* Wl1 = (const float*)d_in[2];
    const float* Wr1 = (const float*)d_in[3];
    const float* b1 = (const float*)d_in[4];
    const float* Wl2 = (const float*)d_in[5];
    const float* Wr2 = (const float*)d_in[6];
    const float* b2 = (const float*)d_in[7];
    float* out = (float*)d_out;

    const int n = in_sizes[0] / 128;   // 100000
    const int E = in_sizes[1] / 2;     // 1600000
    const int* src = ei;
    const int* dst = ei + E;
    const int NB = (n + 255) >> BK_SH;

    // workspace (4B units, 64-aligned):
    // bcursor[512] | rs_beg[n] | rs_end[n] | recs[NB*CAPR] | perm[NB*CAPR]
    //   | wl1b | wr1b | wcat | fb[n*64 bf16 = y1b] | hbuf[n*64 bf16 = hb]
    //   | zf[n*64 f32]
    char* wsb = (char*)d_ws;
    auto A = [](size_t v) { return (v + 63) & ~(size_t)63; };
    int* bcursor = (int*)wsb;                      size_t o = NBMAX;
    int* rs_beg = (int*)wsb + o;                   o += A(n);
    int* rs_end = (int*)wsb + o;                   o += A(n);
    uint_t* recs = (uint_t*)((int*)wsb + o);       o += (size_t)NB * CAPR;
    int* perm = (int*)wsb + o;                     o += (size_t)NB * CAPR;
    ushort_t* wl1b = (ushort_t*)((int*)wsb + o);   o += 4096;
    ushort_t* wr1b = (ushort_t*)((int*)wsb + o);   o += 4096;
    ushort_t* wcat = (ushort_t*)((int*)wsb + o);   o += 8192;
    ushort_t* fb = (ushort_t*)((int*)wsb + o);     o += A((size_t)n * 32);
    ushort_t* hbuf = (ushort_t*)((int*)wsb + o);   o += A((size_t)n * 32);
    float* zf = (float*)wsb + o;                   // n*64 f32

    // ---- weight conversion + cursor seed ----
    cvt_w_kernel<<<64, TPB, 0, stream>>>(Wl1, Wr1, Wl2, Wr2, wl1b, wr1b, wcat, bcursor);

    // ---- FAT: bin_scatter (blocks < SB) || dual_lin (blocks >= SB) ----
    const int SB = (E + TILE - 1) / TILE;
    const int LB = (n + 127) / 128;
    fat_kernel<<<SB + LB, TPB, 0, stream>>>(src, dst, bcursor, recs, E, NB, SB,
                                            x, wl1b, wr1b, fb, zf, n);

    // ---- per-bucket CSR finalize ----
    bucket_build_kernel<<<NB, TPB, 0, stream>>>(recs, bcursor, rs_beg, rs_end, perm, n);

    const int mblocks = (int)(((long long)n * 8 + TPB - 1) / TPB);
    const int oblocks = (n + 63) / 64;

    // hb = bf16(relu(mean(y1b) + b1 + zf))
    csr_mean8_kernel<<<mblocks, TPB, 0, stream>>>(fb, rs_beg, rs_end, perm, zf, b1, hbuf, n);
    // out = [mean(hb)|hb] @ wcat^T + b2  (mean2 fused via LDS)
    out_fused_kernel<<<oblocks, TPB, 0, stream>>>(hbuf, rs_beg, rs_end, perm, wcat, b2, out, n);
}